// Round 4
// baseline (30.610 us; speedup 1.0000x reference)
//
#include <hip/hip_runtime.h>
#include <hip/hip_bf16.h>

#define NB 32        // batch (docs)
#define NT 4096      // tokens per doc
#define NH 256       // hidden
#define NS 256       // MAX_SENTS

// ---------------------------------------------------------------------------
// Kernel A: per-doc boundary scan (32 blocks x 256 threads).
// Thread owns 16 tokens (4x int4 coalesced). Intra-wave inclusive scan via
// __shfl_up, cross-wave fixup via 4-entry LDS (2 barriers). Writes to ws:
//   bpos[b][0] = -1 sentinel, bpos[b][1+i] = token pos of boundary i
//   dlen[b]    = min(count, NS)
// and doc_lens (float, raw count) into the d_out tail.
// ---------------------------------------------------------------------------
__global__ void hie_scan_kernel(const int* __restrict__ batch_x,
                                int* __restrict__ bpos,
                                int* __restrict__ dlen,
                                float* __restrict__ dout) {
    const int b    = blockIdx.x;
    const int tid  = threadIdx.x;
    const int wid  = tid >> 6;
    const int lane = tid & 63;

    __shared__ int sm_w[5];

    const int  base = tid * 16;
    const int4* rp  = reinterpret_cast<const int4*>(batch_x + (size_t)b * NT + base);
    int flags = 0, cnt = 0;
#pragma unroll
    for (int i = 0; i < 4; ++i) {
        int4 v = rp[i];
        int f0 = (v.x == 1), f1 = (v.y == 1), f2 = (v.z == 1), f3 = (v.w == 1);
        flags |= (f0 << (4 * i)) | (f1 << (4 * i + 1)) | (f2 << (4 * i + 2)) | (f3 << (4 * i + 3));
        cnt   += f0 + f1 + f2 + f3;
    }

    int inc = cnt;
#pragma unroll
    for (int off = 1; off < 64; off <<= 1) {
        int u = __shfl_up(inc, off, 64);
        if (lane >= off) inc += u;
    }
    if (lane == 63) sm_w[wid] = inc;
    __syncthreads();
    if (tid == 0) {
        int run = 0;
#pragma unroll
        for (int w = 0; w < 4; ++w) { int t = sm_w[w]; sm_w[w] = run; run += t; }
        sm_w[4] = run;
        bpos[b * (NS + 1)] = -1;                       // sentinel
        dlen[b] = run > NS ? NS : run;
        dout[(size_t)NB * NS * NH + b] = (float)run;   // doc_lens output
    }
    __syncthreads();

    int idx = (inc - cnt) + sm_w[wid];
#pragma unroll
    for (int i = 0; i < 16; ++i) {
        if ((flags >> i) & 1) {
            if (idx < NS) bpos[b * (NS + 1) + 1 + idx] = base + i;
            ++idx;
        }
    }
}

// ---------------------------------------------------------------------------
// Kernel B: pooling. Grid (NS, NB), 256 threads = 4 waves, ONE sentence per
// block. Wave w accumulates rows start+w, start+w+4, ... (unroll-2 -> 2 loads
// in flight per wave, 8 per sentence). Lane l covers h=4l..4l+3 via float4.
// Cross-wave reduce through 4 KB LDS; 256 threads then store 256 contiguous
// floats. Sentences >= dlen zero-fill their output row (d_out fully
// rewritten every call).
// ---------------------------------------------------------------------------
__global__ void hie_pool_kernel(const float* __restrict__ x,
                                const int* __restrict__ bpos,
                                const int* __restrict__ dlen,
                                float* __restrict__ out) {
    const int b    = blockIdx.y;
    const int s    = blockIdx.x;
    const int tid  = threadIdx.x;
    const int wid  = tid >> 6;
    const int lane = tid & 63;

    float* orow = out + ((size_t)b * NS + s) * NH;

    const int L = dlen[b];
    if (s >= L) {
        orow[tid] = 0.0f;
        return;
    }

    const int start = bpos[b * (NS + 1) + s] + 1;
    const int end   = bpos[b * (NS + 1) + s + 1];
    const int n     = end - start + 1;

    // wave w handles rows start+w, start+w+4, ...
    const float4* p = reinterpret_cast<const float4*>(
                          x + ((size_t)b * NT + start + wid) * NH) + lane;
    const int myrows = (n - wid + 3) >> 2;             // rows for this wave
    float4 a0 = make_float4(0.f, 0.f, 0.f, 0.f);
    float4 a1 = make_float4(0.f, 0.f, 0.f, 0.f);
    int k = 0;
    for (; k + 2 <= myrows; k += 2) {
        float4 v0 = p[0];
        float4 v1 = p[4 * (NH / 4)];
        a0.x += v0.x; a0.y += v0.y; a0.z += v0.z; a0.w += v0.w;
        a1.x += v1.x; a1.y += v1.y; a1.z += v1.z; a1.w += v1.w;
        p += 8 * (NH / 4);
    }
    if (k < myrows) {
        float4 v0 = p[0];
        a0.x += v0.x; a0.y += v0.y; a0.z += v0.z; a0.w += v0.w;
    }
    a0.x += a1.x; a0.y += a1.y; a0.z += a1.z; a0.w += a1.w;

    __shared__ float4 smp[4][64];
    smp[wid][lane] = a0;
    __syncthreads();

    // thread tid -> output element h = tid = (l<<2)|c ; sum the 4 wave partials
    const float* smf = reinterpret_cast<const float*>(smp);
    float v = smf[tid] + smf[256 + tid] + smf[512 + tid] + smf[768 + tid];
    orow[tid] = v * (1.0f / (float)n);
}

extern "C" void kernel_launch(void* const* d_in, const int* in_sizes, int n_in,
                              void* d_out, int out_size, void* d_ws, size_t ws_size,
                              hipStream_t stream) {
    const float* hie_ins = (const float*)d_in[0];
    const int*   batch_x = (const int*)d_in[1];
    float*       out     = (float*)d_out;

    int* bpos = (int*)d_ws;                 // NB*(NS+1) ints
    int* dlen = bpos + NB * (NS + 1);       // NB ints

    hie_scan_kernel<<<dim3(NB), dim3(256), 0, stream>>>(batch_x, bpos, dlen, out);
    hie_pool_kernel<<<dim3(NS, NB), dim3(256), 0, stream>>>(hie_ins, bpos, dlen, out);
}